// Round 6
// baseline (455.066 us; speedup 1.0000x reference)
//
#include <hip/hip_runtime.h>
#include <hip/hip_bf16.h>

// Problem constants (from reference)
#define BATCH    2048
#define N_LABELS 10000
#define HIDDEN   768
#define N_EDGES  20000
#define PENALTY  1e-4f

constexpr int THREADS   = 256;
constexpr int N4        = BATCH * N_LABELS / 4;   // 5,120,000 float4 pairs
constexpr int BCE_K     = 10;                     // float4s per thread
constexpr int BCE_STRIDE = N4 / BCE_K;            // 512,000 threads
constexpr int BCE_BLOCKS = BCE_STRIDE / THREADS;  // 2000 (exact, no tail)
constexpr int EDGES_PER_BLOCK = THREADS / 64;     // 4 waves -> 4 edges/block
constexpr int REG_BLOCKS = N_EDGES / EDGES_PER_BLOCK;     // 5000
constexpr int TOTAL_BLOCKS = BCE_BLOCKS + REG_BLOCKS;     // 7000

// stable softplus(x) - t*x via raw HW transcendentals:
// softplus(x) = max(x,0) + ln2 * log2(1 + 2^(-|x|*log2e))
__device__ __forceinline__ float bce_term(float x, float t) {
    float e = __builtin_amdgcn_exp2f(fabsf(x) * -1.44269504f); // e^{-|x|}
    float l = __builtin_amdgcn_logf(1.0f + e);                 // log2(1+e)
    return fmaxf(x, 0.0f) + 0.69314718f * l - t * x;
}

__device__ __forceinline__ float wave_reduce(float v) {
#pragma unroll
    for (int o = 32; o > 0; o >>= 1) v += __shfl_down(v, o, 64);
    return v;
}

// Round-3 structure (best timed: 48.2us) + last-block finalize to kill the
// second launch. r5 lesson: 7000 fp atomicAdds to ONE line serialized the
// grid (105us replay with ~0 HBM traffic) — so partials are plain stores
// (+threadfence for cross-XCD visibility), one int counter atomic per block,
// and the last block sums partials in FIXED order (bitwise deterministic)
// via agent-scope atomic loads (bypass possibly-stale local L2).
template <bool USE_ATOMIC>
__global__ void __launch_bounds__(THREADS)
fused_kernel(const float4* __restrict__ x4, const float4* __restrict__ t4,
             const float* __restrict__ params, const int* __restrict__ pidx,
             const int* __restrict__ cidx, float* __restrict__ partials,
             unsigned int* __restrict__ counter, float* __restrict__ out) {
    const int lane = threadIdx.x & 63;
    const int w    = threadIdx.x >> 6;
    __shared__ float s[THREADS / 64];
    __shared__ bool  lastBlock;

    float acc = 0.0f;
    float scale;
    if (blockIdx.x < BCE_BLOCKS) {
        // ---------- BCE: mean(softplus(x) - t*x) ----------
        const int tid = blockIdx.x * THREADS + threadIdx.x;
        float4 xs[BCE_K], ts[BCE_K];
#pragma unroll
        for (int j = 0; j < BCE_K; ++j) xs[j] = x4[tid + j * BCE_STRIDE];
#pragma unroll
        for (int j = 0; j < BCE_K; ++j) ts[j] = t4[tid + j * BCE_STRIDE];
#pragma unroll
        for (int j = 0; j < BCE_K; ++j) {
            acc += bce_term(xs[j].x, ts[j].x) + bce_term(xs[j].y, ts[j].y) +
                   bce_term(xs[j].z, ts[j].z) + bce_term(xs[j].w, ts[j].w);
        }
        scale = 1.0f / ((float)BATCH * (float)N_LABELS);
    } else {
        // ---- reg: 0.5*PENALTY * sum ||params[p]-params[c]||^2, 1 wave/edge ----
        const int edge = (blockIdx.x - BCE_BLOCKS) * EDGES_PER_BLOCK + w;
        const int p = pidx[edge];
        const int c = cidx[edge];
        const float4* rp = (const float4*)(params + (size_t)p * HIDDEN);
        const float4* rc = (const float4*)(params + (size_t)c * HIDDEN);

        float4 a[3], b[3];
#pragma unroll
        for (int j = 0; j < 3; ++j) a[j] = rp[j * 64 + lane];
#pragma unroll
        for (int j = 0; j < 3; ++j) b[j] = rc[j * 64 + lane];
#pragma unroll
        for (int j = 0; j < 3; ++j) {
            float dx = a[j].x - b[j].x, dy = a[j].y - b[j].y;
            float dz = a[j].z - b[j].z, dw = a[j].w - b[j].w;
            acc = fmaf(dx, dx, acc);
            acc = fmaf(dy, dy, acc);
            acc = fmaf(dz, dz, acc);
            acc = fmaf(dw, dw, acc);
        }
        scale = 0.5f * PENALTY;
    }

    acc = wave_reduce(acc);
    if (lane == 0) s[w] = acc;
    __syncthreads();

    if (USE_ATOMIC) {
        if (threadIdx.x == 0)
            atomicAdd(out, (s[0] + s[1] + s[2] + s[3]) * scale);
        return;
    }

    if (threadIdx.x == 0) {
        partials[blockIdx.x] = (s[0] + s[1] + s[2] + s[3]) * scale;
        __threadfence();  // make the store device-visible (cross-XCD)
        unsigned int old = __hip_atomic_fetch_add(
            counter, 1u, __ATOMIC_ACQ_REL, __HIP_MEMORY_SCOPE_AGENT);
        lastBlock = (old == (unsigned int)(TOTAL_BLOCKS - 1));
    }
    __syncthreads();

    if (lastBlock) {
        // final reduce: fixed order -> deterministic; agent-scope loads
        // bypass this XCD's (possibly stale) L2.
        float a2 = 0.0f;
        for (int i = threadIdx.x; i < TOTAL_BLOCKS; i += THREADS)
            a2 += __hip_atomic_load(&partials[i], __ATOMIC_RELAXED,
                                    __HIP_MEMORY_SCOPE_AGENT);
        a2 = wave_reduce(a2);
        if (lane == 0) s[w] = a2;
        __syncthreads();
        if (threadIdx.x == 0) out[0] = s[0] + s[1] + s[2] + s[3];
    }
}

extern "C" void kernel_launch(void* const* d_in, const int* in_sizes, int n_in,
                              void* d_out, int out_size, void* d_ws, size_t ws_size,
                              hipStream_t stream) {
    const float* logits  = (const float*)d_in[0];
    const float* targets = (const float*)d_in[1];
    const float* params  = (const float*)d_in[2];
    const int*   pidx    = (const int*)d_in[3];
    const int*   cidx    = (const int*)d_in[4];
    float* out = (float*)d_out;

    const size_t need = sizeof(unsigned int) + (size_t)TOTAL_BLOCKS * sizeof(float);
    if (ws_size >= need) {
        unsigned int* counter = (unsigned int*)d_ws;
        float* partials = (float*)((char*)d_ws + sizeof(unsigned int) * 4); // keep 16B align
        hipMemsetAsync(d_ws, 0, sizeof(unsigned int), stream);  // reset counter each call
        fused_kernel<false><<<TOTAL_BLOCKS, THREADS, 0, stream>>>(
            (const float4*)logits, (const float4*)targets, params, pidx, cidx,
            partials, counter, out);
    } else {
        hipMemsetAsync(d_out, 0, sizeof(float), stream);
        fused_kernel<true><<<TOTAL_BLOCKS, THREADS, 0, stream>>>(
            (const float4*)logits, (const float4*)targets, params, pidx, cidx,
            nullptr, nullptr, out);
    }
}

// Round 7
// 45.656 us; speedup vs baseline: 9.9673x; 9.9673x over previous
//
#include <hip/hip_runtime.h>
#include <hip/hip_bf16.h>

// Problem constants (from reference)
#define BATCH    2048
#define N_LABELS 10000
#define HIDDEN   768
#define N_EDGES  20000
#define PENALTY  1e-4f

constexpr int THREADS = 256;
constexpr int WAVES   = THREADS / 64;             // 4
constexpr int D       = 4;                        // pipeline depth (stages)
constexpr int T       = 10;                       // tiles per wave
constexpr int TILE    = 1024;                     // bytes/tile/array (64 lanes x 16B)
constexpr int STAGE   = 2 * TILE;                 // x-tile + t-tile
constexpr int N4      = BATCH * N_LABELS / 4;     // 5,120,000 float4
constexpr int BCE_TILES  = N4 / 64;               // 80,000 tiles
constexpr int BCE_WAVES  = BCE_TILES / T;         // 8,000 waves
constexpr int BCE_BLOCKS = BCE_WAVES / WAVES;     // 2,000 blocks (exact)
constexpr int EDGES_PER_BLOCK = WAVES;            // 4 edges/block (1 wave/edge)
constexpr int REG_BLOCKS = N_EDGES / EDGES_PER_BLOCK;   // 5,000
constexpr int TOTAL_BLOCKS = BCE_BLOCKS + REG_BLOCKS;   // 7,000
constexpr int FIN_THREADS = 1024;

// stable softplus(x) - t*x via raw HW transcendentals:
// softplus(x) = max(x,0) + ln2 * log2(1 + 2^(-|x|*log2e))
__device__ __forceinline__ float bce_term(float x, float t) {
    float e = __builtin_amdgcn_exp2f(fabsf(x) * -1.44269504f); // e^{-|x|}
    float l = __builtin_amdgcn_logf(1.0f + e);                 // log2(1+e)
    return fmaxf(x, 0.0f) + 0.69314718f * l - t * x;
}

__device__ __forceinline__ float wave_reduce(float v) {
#pragma unroll
    for (int o = 32; o > 0; o >>= 1) v += __shfl_down(v, o, 64);
    return v;
}

// async global->LDS DMA, 16B per lane: LDS dest = uniform base + lane*16,
// global src = per-lane address. In-flight depth counted in vmcnt, not VGPRs.
typedef const __attribute__((address_space(1))) void* gaddr_t;
typedef __attribute__((address_space(3))) void*       laddr_t;
__device__ __forceinline__ void gload16(const void* g, void* l) {
    __builtin_amdgcn_global_load_lds((gaddr_t)g, (laddr_t)l, 16, 0, 0);
}

// Blocks [0,BCE_BLOCKS): BCE via per-wave DMA pipeline (no barriers — each
// wave owns a private D-stage LDS region, consumes with counted vmcnt).
// Blocks [BCE_BLOCKS,TOTAL): edge regularizer, 1 wave/edge direct loads.
// r5/r6 lesson: NO per-block device-scope fences/atomic chains — partials to
// ws, separate tiny finalize kernel (r3 structure, best timed).
template <bool USE_ATOMIC>
__global__ void __launch_bounds__(THREADS)
fused_kernel(const float4* __restrict__ x4, const float4* __restrict__ t4,
             const float* __restrict__ params, const int* __restrict__ pidx,
             const int* __restrict__ cidx, float* __restrict__ dst) {
    const int lane = threadIdx.x & 63;
    const int w    = threadIdx.x >> 6;
    __shared__ char  stage_mem[WAVES * D * STAGE];  // 32 KiB
    __shared__ float s[WAVES];

    float acc = 0.0f;
    float scale;
    if (blockIdx.x < BCE_BLOCKS) {
        // ---------- BCE: mean(softplus(x) - t*x), DMA-pipelined ----------
        const int wid = blockIdx.x * WAVES + w;     // 0..7999
        const char* xg = (const char*)x4 + (size_t)wid * (T * TILE);
        const char* tg = (const char*)t4 + (size_t)wid * (T * TILE);
        char* my = stage_mem + w * (D * STAGE);     // wave-private region
        const int lo = lane * 16;

        // prologue: D tiles in flight (2 DMA ops per tile)
#pragma unroll
        for (int p = 0; p < D; ++p) {
            gload16(xg + p * TILE + lo, my + p * STAGE);
            gload16(tg + p * TILE + lo, my + p * STAGE + TILE);
        }

        // steady state: wait for oldest tile only (vmcnt(6) = 3 tiles still
        // in flight), consume, reissue into the freed stage. Tail drains
        // 4 -> 2 -> 0. Never vmcnt(0) in steady state.
#define BCE_STEP(TI, WC)                                                     \
        {                                                                    \
            asm volatile("s_waitcnt vmcnt(" #WC ")" ::: "memory");           \
            const float4 xv = *(const float4*)(my + ((TI) & (D - 1)) * STAGE + lo);          \
            const float4 tv = *(const float4*)(my + ((TI) & (D - 1)) * STAGE + TILE + lo);   \
            acc += bce_term(xv.x, tv.x) + bce_term(xv.y, tv.y) +             \
                   bce_term(xv.z, tv.z) + bce_term(xv.w, tv.w);              \
            if ((TI) + D < T) {                                              \
                gload16(xg + ((TI) + D) * TILE + lo, my + ((TI) & (D - 1)) * STAGE);         \
                gload16(tg + ((TI) + D) * TILE + lo, my + ((TI) & (D - 1)) * STAGE + TILE);  \
            }                                                                \
        }
        BCE_STEP(0, 6) BCE_STEP(1, 6) BCE_STEP(2, 6) BCE_STEP(3, 6)
        BCE_STEP(4, 6) BCE_STEP(5, 6) BCE_STEP(6, 6)
        BCE_STEP(7, 4) BCE_STEP(8, 2) BCE_STEP(9, 0)
#undef BCE_STEP
        scale = 1.0f / ((float)BATCH * (float)N_LABELS);
    } else {
        // ---- reg: 0.5*PENALTY * sum ||params[p]-params[c]||^2, 1 wave/edge ----
        const int edge = (blockIdx.x - BCE_BLOCKS) * EDGES_PER_BLOCK + w;
        const int p = pidx[edge];
        const int c = cidx[edge];
        const float4* rp = (const float4*)(params + (size_t)p * HIDDEN);
        const float4* rc = (const float4*)(params + (size_t)c * HIDDEN);

        float4 a[3], b[3];
#pragma unroll
        for (int j = 0; j < 3; ++j) a[j] = rp[j * 64 + lane];
#pragma unroll
        for (int j = 0; j < 3; ++j) b[j] = rc[j * 64 + lane];
#pragma unroll
        for (int j = 0; j < 3; ++j) {
            float dx = a[j].x - b[j].x, dy = a[j].y - b[j].y;
            float dz = a[j].z - b[j].z, dw = a[j].w - b[j].w;
            acc = fmaf(dx, dx, acc);
            acc = fmaf(dy, dy, acc);
            acc = fmaf(dz, dz, acc);
            acc = fmaf(dw, dw, acc);
        }
        scale = 0.5f * PENALTY;
    }

    acc = wave_reduce(acc);
    if (lane == 0) s[w] = acc;
    __syncthreads();
    if (threadIdx.x == 0) {
        float b = (s[0] + s[1] + s[2] + s[3]) * scale;
        if (USE_ATOMIC) atomicAdd(dst, b);
        else            dst[blockIdx.x] = b;
    }
}

// ---------------- finalize: deterministic sum of partials ----------------
__global__ void __launch_bounds__(FIN_THREADS)
finalize_kernel(const float* __restrict__ partials, int n, float* __restrict__ out) {
    float acc = 0.0f;
    for (int i = threadIdx.x; i < n; i += blockDim.x) acc += partials[i];
    acc = wave_reduce(acc);
    __shared__ float s[FIN_THREADS / 64];
    const int lane = threadIdx.x & 63, w = threadIdx.x >> 6;
    if (lane == 0) s[w] = acc;
    __syncthreads();
    if (threadIdx.x == 0) {
        float b = 0.0f;
#pragma unroll
        for (int i = 0; i < FIN_THREADS / 64; ++i) b += s[i];
        out[0] = b;
    }
}

extern "C" void kernel_launch(void* const* d_in, const int* in_sizes, int n_in,
                              void* d_out, int out_size, void* d_ws, size_t ws_size,
                              hipStream_t stream) {
    const float* logits  = (const float*)d_in[0];
    const float* targets = (const float*)d_in[1];
    const float* params  = (const float*)d_in[2];
    const int*   pidx    = (const int*)d_in[3];
    const int*   cidx    = (const int*)d_in[4];
    float* out = (float*)d_out;

    const size_t need = (size_t)TOTAL_BLOCKS * sizeof(float);
    if (ws_size >= need) {
        float* partials = (float*)d_ws;
        fused_kernel<false><<<TOTAL_BLOCKS, THREADS, 0, stream>>>(
            (const float4*)logits, (const float4*)targets, params, pidx, cidx,
            partials);
        finalize_kernel<<<1, FIN_THREADS, 0, stream>>>(partials, TOTAL_BLOCKS, out);
    } else {
        hipMemsetAsync(d_out, 0, sizeof(float), stream);
        fused_kernel<true><<<TOTAL_BLOCKS, THREADS, 0, stream>>>(
            (const float4*)logits, (const float4*)targets, params, pidx, cidx,
            out);
    }
}